// Round 10
// baseline (103.276 us; speedup 1.0000x reference)
//
#include <hip/hip_runtime.h>

// B=2, Hi=Wi=64, Di=32, C=16, F=8, strides (2,2,2), k=3x3x3, Ho=Wo=128, Do=64.
constexpr int Bc  = 2;
constexpr int HiC = 64, WiC = 64, DiC = 32;
constexpr int Cc  = 16, Fc  = 8;
constexpr int HoC = 128, WoC = 128, DoC = 64;
constexpr int IMG_ELEMS = Bc * HiC * WiC * DiC * Cc;   // 4,194,304 bf16 elems

typedef __attribute__((ext_vector_type(8))) short short8;   // 8 bf16 = A/B frag
typedef __attribute__((ext_vector_type(4))) float f32x4;    // MFMA accumulator

__device__ alignas(16) const float FZERO[8] = {0, 0, 0, 0, 0, 0, 0, 0};

__device__ __forceinline__ unsigned pk2(float x, float y) {   // RNE f32x2 -> bf16x2
    unsigned ux = __float_as_uint(x), uy = __float_as_uint(y);
    ux += ((ux >> 16) & 1u) + 0x7FFFu;
    uy += ((uy >> 16) & 1u) + 0x7FFFu;
    return (ux >> 16) | (uy & 0xFFFF0000u);
}
__device__ __forceinline__ short8 pack8(float4 a, float4 b) {
    union { unsigned u[4]; short8 s; } r;
    r.u[0] = pk2(a.x, a.y); r.u[1] = pk2(a.z, a.w);
    r.u[2] = pk2(b.x, b.y); r.u[3] = pk2(b.z, b.w);
    return r.s;
}

// prepass: images f32 -> bf16 into ws + 64 B zero row at tail (OOB-tap target,
// selected with one 32-bit offset cndmask).
__global__ __launch_bounds__(256)
void imgcvt(const float4* __restrict__ in, uint2* __restrict__ outv, int n4) {
    int i = blockIdx.x * 256 + threadIdx.x;
    if (i < n4) {
        float4 v = in[i];
        uint2 o; o.x = pk2(v.x, v.y); o.y = pk2(v.z, v.w);
        outv[i] = o;
    } else if (i < n4 + 8) {
        uint2 z; z.x = 0u; z.y = 0u;
        outv[i] = z;                       // zero row: elems [IMG_ELEMS, +32)
    }
}

// Wave = 4 same-parity columns. MFMA packing as rounds 7-9 (verified).
// Round-10 change: phase 2a computes ALL columns' MFMAs with NO wave_barriers
// (the per-column barriers were serializing the 4 columns' tap loads);
// phase 2b does the 4 LDS-transpose epilogues afterwards.
template<int CLS, int CVT>
__device__ __forceinline__ void doCols(const short* __restrict__ img16,
                                       const float* __restrict__ img32,
                                       const int*   __restrict__ bp,
                                       const float* __restrict__ kern,
                                       float*       __restrict__ out,
                                       float*       __restrict__ ldsw,
                                       int b, int ho, int wo0, int lane) {
    constexpr int NP = (CLS == 0) ? 1 : ((CLS == 3) ? 4 : 2);
    constexpr int OP = (NP + 1) / 2;
    constexpr int KH[4][4] = {{1,0,0,0},{1,1,0,0},{0,2,0,0},{0,0,2,2}};
    constexpr int KW[4][4] = {{1,0,0,0},{0,2,0,0},{1,1,0,0},{0,2,0,2}};

    const int quad = lane >> 4, n = lane & 15;
    const int half = quad >> 1, chalf = quad & 1;   // k-half, channel-half

    // ---- B fragments in-register from f32 kern (amortized over 4 columns) ----
    short8 bE[NP], bO[OP];
    #pragma unroll
    for (int p = 0; p < NP; ++p) {
        const int kp = KH[CLS][p] * 3 + KW[CLS][p];
        const float* wp = (n < Fc)
            ? kern + (kp * 3 + 2 * half) * 128 + n * 16 + chalf * 8 : FZERO;
        bE[p] = pack8(*(const float4*)wp, *(const float4*)(wp + 4));
    }
    #pragma unroll
    for (int pp = 0; pp < OP; ++pp) {
        const int  PA   = (2 * pp < NP) ? 2 * pp : 0;
        const bool hasB = (2 * pp + 1) < NP;
        const int  PB   = hasB ? (2 * pp + 1) : 0;
        const int kpa = KH[CLS][PA] * 3 + KW[CLS][PA];
        const int kpb = KH[CLS][PB] * 3 + KW[CLS][PB];
        const int kp  = half ? kpb : kpa;
        const bool v  = (n < Fc) && (!half || hasB);
        const float* wp = v ? kern + (kp * 3 + 1) * 128 + n * 16 + chalf * 8 : FZERO;
        bO[pp] = pack8(*(const float4*)wp, *(const float4*)(wp + 4));
    }

    // ---- phase 1: ALL scalar loads + sentinel folds for all 4 columns ----
    int colx[4], qv[4], sE[4][NP], sO[4][NP], pxo[4][NP];
    #pragma unroll
    for (int cc = 0; cc < 4; ++cc) {
        const int wo = wo0 + 2 * cc;
        colx[cc]  = __builtin_amdgcn_readfirstlane((b * HoC + ho) * WoC + wo);
        const int bp_col = bp[colx[cc]];             // uniform -> s_load
        qv[cc] = (bp_col + 1) & 1;
        const int baseE = (bp_col + qv[cc] + 1) >> 1;   // di(kd0) = baseE+m-bpg
        const int baseO = (bp_col + 1 - qv[cc]) >> 1;   // di(kd1) = baseO+m-bpg
        #pragma unroll
        for (int p = 0; p < NP; ++p) {
            const int kh = KH[CLS][p], kw = KW[CLS][p];
            int hi = (ho + 1 - kh) >> 1; hi = hi > HiC - 1 ? HiC - 1 : hi;
            int wi = (wo + 1 - kw) >> 1; wi = wi > WiC - 1 ? WiC - 1 : wi;
            const bool pv = (kh != 0 || ho + 1 < HoC) && (kw != 0 || wo + 1 < WoC);
            const int sidx =
                __builtin_amdgcn_readfirstlane((b * HoC + 2 * hi) * WoC + 2 * wi);
            const int bpg = bp[sidx] >> 1;           // uniform -> s_load
            sE[cc][p]  = pv ? baseE - bpg : -100000; // sentinel folds validity
            sO[cc][p]  = pv ? baseO - bpg : -100000;
            pxo[cc][p] = __builtin_amdgcn_readfirstlane(
                             ((b * HiC + hi) * WiC + wi) * (DiC * Cc));
        }
    }

    // ---- phase 2a: ALL columns' taps + MFMAs, no barriers ----
    f32x4 aE[4][2], aO[4][2];
    #pragma unroll
    for (int cc = 0; cc < 4; ++cc)
        #pragma unroll
        for (int g = 0; g < 2; ++g) {
            aE[cc][g] = (f32x4){0.f, 0.f, 0.f, 0.f};
            aO[cc][g] = (f32x4){0.f, 0.f, 0.f, 0.f};
        }

    #pragma unroll
    for (int cc = 0; cc < 4; ++cc) {
        #pragma unroll
        for (int g = 0; g < 2; ++g) {
            #pragma unroll
            for (int p = 0; p < NP; ++p) {           // E: kd = 2*half
                const int  di = sE[cc][p] + 16 * g + n - half;
                const bool ok = (unsigned)di < (unsigned)DiC;
                short8 a;
                if constexpr (CVT) {
                    const float* ap = ok ? img32 + pxo[cc][p] + di * Cc + chalf * 8 : FZERO;
                    a = pack8(*(const float4*)ap, *(const float4*)(ap + 4));
                } else {
                    const int off = ok ? pxo[cc][p] + di * Cc + chalf * 8 : IMG_ELEMS;
                    a = *(const short8*)(img16 + off);
                }
                aE[cc][g] = __builtin_amdgcn_mfma_f32_16x16x32_bf16(a, bE[p], aE[cc][g], 0, 0, 0);
            }
            #pragma unroll
            for (int pp = 0; pp < OP; ++pp) {        // O: k-halves = two positions
                const int  PA   = (2 * pp < NP) ? 2 * pp : 0;
                const bool hasB = (2 * pp + 1) < NP;
                const int  PB   = hasB ? (2 * pp + 1) : 0;
                const int  sOs  = half ? (hasB ? sO[cc][PB] : -100000) : sO[cc][PA];
                const int  pxs  = half ? pxo[cc][PB] : pxo[cc][PA];
                const int  di = sOs + 16 * g + n;
                const bool ok = (unsigned)di < (unsigned)DiC;
                short8 a;
                if constexpr (CVT) {
                    const float* ap = ok ? img32 + pxs + di * Cc + chalf * 8 : FZERO;
                    a = pack8(*(const float4*)ap, *(const float4*)(ap + 4));
                } else {
                    const int off = ok ? pxs + di * Cc + chalf * 8 : IMG_ELEMS;
                    a = *(const short8*)(img16 + off);
                }
                aO[cc][g] = __builtin_amdgcn_mfma_f32_16x16x32_bf16(a, bO[pp], aO[cc][g], 0, 0, 0);
            }
        }
    }

    // ---- phase 2b: per-column LDS transpose + store (barriers safe here) ----
    #pragma unroll
    for (int cc = 0; cc < 4; ++cc) {
        const int q = qv[cc];
        __builtin_amdgcn_wave_barrier();
        if (n < Fc) {
            #pragma unroll
            for (int g = 0; g < 2; ++g) {
                #pragma unroll
                for (int r = 0; r < 4; ++r) {
                    const int m2 = 16 * g + quad * 4 + r;
                    ldsw[(2 * m2 + q) * Fc + n]     = aE[cc][g][r];
                    ldsw[(2 * m2 + 1 - q) * Fc + n] = aO[cc][g][r];
                }
            }
        }
        __builtin_amdgcn_wave_barrier();
        float* outc = out + (size_t)colx[cc] * (DoC * Fc);
        *(float4*)(outc + lane * 8)     = *(const float4*)(ldsw + lane * 8);
        *(float4*)(outc + lane * 8 + 4) = *(const float4*)(ldsw + lane * 8 + 4);
        __builtin_amdgcn_wave_barrier();
    }
}

template<int CVT>
__global__ __launch_bounds__(256, 3)
void sconv_mfma(const short* __restrict__ img16, const float* __restrict__ img32,
                const int* __restrict__ bp, const float* __restrict__ kern,
                float* __restrict__ out) {
    __shared__ float lds[4 * DoC * Fc];   // 8 KiB, one 2 KiB slice per wave
    const int t = threadIdx.x, wv = t >> 6, lane = t & 63;
    const int b = blockIdx.z, ho = blockIdx.y;
    // block covers 16 wo; wave wv covers 4 same-parity columns wo0 + {0,2,4,6}
    const int wo0 = (blockIdx.x << 4) + (wv & 1) + ((wv >> 1) << 3);
    float* ldsw = lds + wv * (DoC * Fc);
    if (ho & 1) {
        if (wv & 1) doCols<3, CVT>(img16, img32, bp, kern, out, ldsw, b, ho, wo0, lane);
        else        doCols<2, CVT>(img16, img32, bp, kern, out, ldsw, b, ho, wo0, lane);
    } else {
        if (wv & 1) doCols<1, CVT>(img16, img32, bp, kern, out, ldsw, b, ho, wo0, lane);
        else        doCols<0, CVT>(img16, img32, bp, kern, out, ldsw, b, ho, wo0, lane);
    }
}

extern "C" void kernel_launch(void* const* d_in, const int* in_sizes, int n_in,
                              void* d_out, int out_size, void* d_ws, size_t ws_size,
                              hipStream_t stream) {
    const float* images = (const float*)d_in[0];
    const int*   bp     = (const int*)d_in[1];
    const float* kern   = (const float*)d_in[2];
    float* out = (float*)d_out;

    const size_t needWs = ((size_t)IMG_ELEMS + 32) * sizeof(short);  // 8 MiB + 64 B

    dim3 grid(WoC / 16, HoC, Bc), block(256);   // 8 x 128 x 2 = 2048 blocks
    if (ws_size >= needWs) {
        // fast path: bf16 image + tail zero row in ws (size-checked; round-5 lesson)
        const int n4 = IMG_ELEMS / 4;                                // 1,048,576
        hipLaunchKernelGGL(imgcvt, dim3(n4 / 256 + 1), dim3(256), 0, stream,
                           (const float4*)images, (uint2*)d_ws, n4);
        hipLaunchKernelGGL((sconv_mfma<0>), grid, block, 0, stream,
                           (const short*)d_ws, images, bp, kern, out);
    } else {
        // fallback: inline f32->bf16 conversion; ws untouched
        hipLaunchKernelGGL((sconv_mfma<1>), grid, block, 0, stream,
                           (const short*)nullptr, images, bp, kern, out);
    }
}

// Round 11
// 101.156 us; speedup vs baseline: 1.0210x; 1.0210x over previous
//
#include <hip/hip_runtime.h>

// B=2, Hi=Wi=64, Di=32, C=16, F=8, strides (2,2,2), k=3x3x3, Ho=Wo=128, Do=64.
// FINAL (round-9 variant, best measured: 99.9 us total, absmax 0.03125).
// Round-10's barrier-removal (all-columns-live) regressed to 103.3 us; reverted.
constexpr int Bc  = 2;
constexpr int HiC = 64, WiC = 64, DiC = 32;
constexpr int Cc  = 16, Fc  = 8;
constexpr int HoC = 128, WoC = 128, DoC = 64;
constexpr int IMG_ELEMS = Bc * HiC * WiC * DiC * Cc;   // 4,194,304 bf16 elems

typedef __attribute__((ext_vector_type(8))) short short8;   // 8 bf16 = A/B frag
typedef __attribute__((ext_vector_type(4))) float f32x4;    // MFMA accumulator

__device__ alignas(16) const float FZERO[8] = {0, 0, 0, 0, 0, 0, 0, 0};

__device__ __forceinline__ unsigned pk2(float x, float y) {   // RNE f32x2 -> bf16x2
    unsigned ux = __float_as_uint(x), uy = __float_as_uint(y);
    ux += ((ux >> 16) & 1u) + 0x7FFFu;
    uy += ((uy >> 16) & 1u) + 0x7FFFu;
    return (ux >> 16) | (uy & 0xFFFF0000u);
}
__device__ __forceinline__ short8 pack8(float4 a, float4 b) {
    union { unsigned u[4]; short8 s; } r;
    r.u[0] = pk2(a.x, a.y); r.u[1] = pk2(a.z, a.w);
    r.u[2] = pk2(b.x, b.y); r.u[3] = pk2(b.z, b.w);
    return r.s;
}

// prepass: images f32 -> bf16 into ws + 64 B zero row at tail (OOB-tap target,
// selected with one 32-bit offset cndmask).
__global__ __launch_bounds__(256)
void imgcvt(const float4* __restrict__ in, uint2* __restrict__ outv, int n4) {
    int i = blockIdx.x * 256 + threadIdx.x;
    if (i < n4) {
        float4 v = in[i];
        uint2 o; o.x = pk2(v.x, v.y); o.y = pk2(v.z, v.w);
        outv[i] = o;
    } else if (i < n4 + 8) {
        uint2 z; z.x = 0u; z.y = 0u;
        outv[i] = z;                       // zero row: elems [IMG_ELEMS, +32)
    }
}

// Wave = 4 same-parity columns. Per column: out[do,f] over (pos,kd,c) packed in
// MFMA K=32. E rows (bp+do+1 even): per position, k-halves = kd0/kd2. O rows
// (kd=1): two positions per MFMA. A: A[m=lane&15][k=quad*8+j]; B: B[k][n=lane&15];
// C/D: col=lane&15, row=quad*4+reg. (verified end-to-end rounds 7-9)
// Phase 1 issues ALL scalar loads (bp_col + bpg, geometric addrs) up front;
// validity is folded into a scalar sentinel so per-tap test is one unsigned cmp.
template<int CLS, int CVT>
__device__ __forceinline__ void doCols(const short* __restrict__ img16,
                                       const float* __restrict__ img32,
                                       const int*   __restrict__ bp,
                                       const float* __restrict__ kern,
                                       float*       __restrict__ out,
                                       float*       __restrict__ ldsw,
                                       int b, int ho, int wo0, int lane) {
    constexpr int NP = (CLS == 0) ? 1 : ((CLS == 3) ? 4 : 2);
    constexpr int OP = (NP + 1) / 2;
    constexpr int KH[4][4] = {{1,0,0,0},{1,1,0,0},{0,2,0,0},{0,0,2,2}};
    constexpr int KW[4][4] = {{1,0,0,0},{0,2,0,0},{1,1,0,0},{0,2,0,2}};

    const int quad = lane >> 4, n = lane & 15;
    const int half = quad >> 1, chalf = quad & 1;   // k-half, channel-half

    // ---- B fragments in-register from f32 kern (amortized over 4 columns) ----
    short8 bE[NP], bO[OP];
    #pragma unroll
    for (int p = 0; p < NP; ++p) {
        const int kp = KH[CLS][p] * 3 + KW[CLS][p];
        const float* wp = (n < Fc)
            ? kern + (kp * 3 + 2 * half) * 128 + n * 16 + chalf * 8 : FZERO;
        bE[p] = pack8(*(const float4*)wp, *(const float4*)(wp + 4));
    }
    #pragma unroll
    for (int pp = 0; pp < OP; ++pp) {
        const int  PA   = (2 * pp < NP) ? 2 * pp : 0;
        const bool hasB = (2 * pp + 1) < NP;
        const int  PB   = hasB ? (2 * pp + 1) : 0;
        const int kpa = KH[CLS][PA] * 3 + KW[CLS][PA];
        const int kpb = KH[CLS][PB] * 3 + KW[CLS][PB];
        const int kp  = half ? kpb : kpa;
        const bool v  = (n < Fc) && (!half || hasB);
        const float* wp = v ? kern + (kp * 3 + 1) * 128 + n * 16 + chalf * 8 : FZERO;
        bO[pp] = pack8(*(const float4*)wp, *(const float4*)(wp + 4));
    }

    // ---- phase 1: ALL scalar loads for all 4 columns ----
    int colx[4], bpcol[4], bpgr[4][NP], pxo[4][NP]; bool pvs[4][NP];
    #pragma unroll
    for (int cc = 0; cc < 4; ++cc) {
        const int wo = wo0 + 2 * cc;
        colx[cc]  = __builtin_amdgcn_readfirstlane((b * HoC + ho) * WoC + wo);
        bpcol[cc] = bp[colx[cc]];                    // uniform -> s_load
        #pragma unroll
        for (int p = 0; p < NP; ++p) {
            const int kh = KH[CLS][p], kw = KW[CLS][p];
            int hi = (ho + 1 - kh) >> 1; hi = hi > HiC - 1 ? HiC - 1 : hi;
            int wi = (wo + 1 - kw) >> 1; wi = wi > WiC - 1 ? WiC - 1 : wi;
            pvs[cc][p] = (kh != 0 || ho + 1 < HoC) && (kw != 0 || wo + 1 < WoC);
            const int sidx =
                __builtin_amdgcn_readfirstlane((b * HoC + 2 * hi) * WoC + 2 * wi);
            bpgr[cc][p] = bp[sidx];                  // uniform -> s_load
            pxo[cc][p]  = __builtin_amdgcn_readfirstlane(
                              ((b * HiC + hi) * WiC + wi) * (DiC * Cc));
        }
    }

    // ---- phase 2: per column taps + MFMA + epilogue ----
    #pragma unroll
    for (int cc = 0; cc < 4; ++cc) {
        const int bp_col = bpcol[cc];
        const int q      = (bp_col + 1) & 1;
        const int baseE  = (bp_col + q + 1) >> 1;    // di(kd0) = baseE+m-bpg
        const int baseO  = (bp_col + 1 - q) >> 1;    // di(kd1) = baseO+m-bpg
        int sE[NP], sO[NP];
        #pragma unroll
        for (int p = 0; p < NP; ++p) {               // sentinel folds validity
            const int bpg = bpgr[cc][p] >> 1;
            sE[p] = pvs[cc][p] ? baseE - bpg : -100000;
            sO[p] = pvs[cc][p] ? baseO - bpg : -100000;
        }

        f32x4 accE[2] = {{0.f,0.f,0.f,0.f},{0.f,0.f,0.f,0.f}};
        f32x4 accO[2] = {{0.f,0.f,0.f,0.f},{0.f,0.f,0.f,0.f}};

        #pragma unroll
        for (int g = 0; g < 2; ++g) {
            #pragma unroll
            for (int p = 0; p < NP; ++p) {           // E: kd = 2*half
                const int  di = sE[p] + 16 * g + n - half;
                const bool ok = (unsigned)di < (unsigned)DiC;
                short8 a;
                if constexpr (CVT) {
                    const float* ap = ok ? img32 + pxo[cc][p] + di * Cc + chalf * 8 : FZERO;
                    a = pack8(*(const float4*)ap, *(const float4*)(ap + 4));
                } else {
                    const int off = ok ? pxo[cc][p] + di * Cc + chalf * 8 : IMG_ELEMS;
                    a = *(const short8*)(img16 + off);
                }
                accE[g] = __builtin_amdgcn_mfma_f32_16x16x32_bf16(a, bE[p], accE[g], 0, 0, 0);
            }
            #pragma unroll
            for (int pp = 0; pp < OP; ++pp) {        // O: k-halves = two positions
                const int  PA   = (2 * pp < NP) ? 2 * pp : 0;
                const bool hasB = (2 * pp + 1) < NP;
                const int  PB   = hasB ? (2 * pp + 1) : 0;
                const int  sOs  = half ? (hasB ? sO[PB] : -100000) : sO[PA];
                const int  pxs  = half ? pxo[cc][PB] : pxo[cc][PA];
                const int  di = sOs + 16 * g + n;
                const bool ok = (unsigned)di < (unsigned)DiC;
                short8 a;
                if constexpr (CVT) {
                    const float* ap = ok ? img32 + pxs + di * Cc + chalf * 8 : FZERO;
                    a = pack8(*(const float4*)ap, *(const float4*)(ap + 4));
                } else {
                    const int off = ok ? pxs + di * Cc + chalf * 8 : IMG_ELEMS;
                    a = *(const short8*)(img16 + off);
                }
                accO[g] = __builtin_amdgcn_mfma_f32_16x16x32_bf16(a, bO[pp], accO[g], 0, 0, 0);
            }
        }

        // Wave-private LDS transpose: C/D (row=quad*4+r, col=n) -> [do][f] rows.
        __builtin_amdgcn_wave_barrier();
        if (n < Fc) {
            #pragma unroll
            for (int g = 0; g < 2; ++g) {
                #pragma unroll
                for (int r = 0; r < 4; ++r) {
                    const int m2 = 16 * g + quad * 4 + r;
                    ldsw[(2 * m2 + q) * Fc + n]     = accE[g][r];
                    ldsw[(2 * m2 + 1 - q) * Fc + n] = accO[g][r];
                }
            }
        }
        __builtin_amdgcn_wave_barrier();
        float* outc = out + (size_t)colx[cc] * (DoC * Fc);
        *(float4*)(outc + lane * 8)     = *(const float4*)(ldsw + lane * 8);
        *(float4*)(outc + lane * 8 + 4) = *(const float4*)(ldsw + lane * 8 + 4);
        __builtin_amdgcn_wave_barrier();
    }
}

template<int CVT>
__global__ __launch_bounds__(256, 3)
void sconv_mfma(const short* __restrict__ img16, const float* __restrict__ img32,
                const int* __restrict__ bp, const float* __restrict__ kern,
                float* __restrict__ out) {
    __shared__ float lds[4 * DoC * Fc];   // 8 KiB, one 2 KiB slice per wave
    const int t = threadIdx.x, wv = t >> 6, lane = t & 63;
    const int b = blockIdx.z, ho = blockIdx.y;
    // block covers 16 wo; wave wv covers 4 same-parity columns wo0 + {0,2,4,6}
    const int wo0 = (blockIdx.x << 4) + (wv & 1) + ((wv >> 1) << 3);
    float* ldsw = lds + wv * (DoC * Fc);
    if (ho & 1) {
        if (wv & 1) doCols<3, CVT>(img16, img32, bp, kern, out, ldsw, b, ho, wo0, lane);
        else        doCols<2, CVT>(img16, img32, bp, kern, out, ldsw, b, ho, wo0, lane);
    } else {
        if (wv & 1) doCols<1, CVT>(img16, img32, bp, kern, out, ldsw, b, ho, wo0, lane);
        else        doCols<0, CVT>(img16, img32, bp, kern, out, ldsw, b, ho, wo0, lane);
    }
}

extern "C" void kernel_launch(void* const* d_in, const int* in_sizes, int n_in,
                              void* d_out, int out_size, void* d_ws, size_t ws_size,
                              hipStream_t stream) {
    const float* images = (const float*)d_in[0];
    const int*   bp     = (const int*)d_in[1];
    const float* kern   = (const float*)d_in[2];
    float* out = (float*)d_out;

    const size_t needWs = ((size_t)IMG_ELEMS + 32) * sizeof(short);  // 8 MiB + 64 B

    dim3 grid(WoC / 16, HoC, Bc), block(256);   // 8 x 128 x 2 = 2048 blocks
    if (ws_size >= needWs) {
        // fast path: bf16 image + tail zero row in ws (size-checked; round-5 lesson)
        const int n4 = IMG_ELEMS / 4;                                // 1,048,576
        hipLaunchKernelGGL(imgcvt, dim3(n4 / 256 + 1), dim3(256), 0, stream,
                           (const float4*)images, (uint2*)d_ws, n4);
        hipLaunchKernelGGL((sconv_mfma<0>), grid, block, 0, stream,
                           (const short*)d_ws, images, bp, kern, out);
    } else {
        // fallback: inline f32->bf16 conversion; ws untouched
        hipLaunchKernelGGL((sconv_mfma<1>), grid, block, 0, stream,
                           (const short*)nullptr, images, bp, kern, out);
    }
}